// Round 5
// baseline (335.173 us; speedup 1.0000x reference)
//
#include <hip/hip_runtime.h>
#include <math.h>

// Capsule routing without materializing u_hat.
//   o[b,n,:] = W_n * (sum_i c[b,n,i] u[b,i,:])
//   logits[b,i,n] = u[b,i,:] . t[b,n,:],  t = W_n^T o_norm
// R5: plain multi-kernel (R4's cooperative launch silently no-oped: output
// stayed zero -> absmax ~ max|ref|; coop is a graph-capture tripwire).
//   k_ot v4: block per (b,n), 2048 blocks, coalesced W reads, one butterfly
//            per row with ILP across 16 rows (R3's was 37us: 64 chained
//            butterflies at 2 waves/SIMD).
//   k_route v5: inner GEMM straight from global (L2/L3-hot), no staging
//            barriers; LDS only for the 18.4KB coefficient tile (R3's was
//            56us: 72KB LDS -> 2 blocks/CU, LDS-throughput-bound).

#define B   64
#define IN  1024
#define ID  256
#define NC  32
#define DC  64
#define CH  8
#define RIT (IN / CH)   // 128 i per chunk

// ---------------------------------------------------------------------------
// sp0[c][b][d] = sum over i-chunk c of u[b][i][d]
__global__ __launch_bounds__(256) void k_sumu(const float* __restrict__ u,
                                              float* __restrict__ sp0) {
    const int c = blockIdx.x, b = blockIdx.y;
    const int d = threadIdx.x;
    const float* up = u + ((size_t)b * IN + (size_t)c * RIT) * ID + d;
    float acc = 0.f;
#pragma unroll 8
    for (int i = 0; i < RIT; ++i) acc += up[(size_t)i * ID];
    sp0[(c * B + b) * ID + d] = acc;
}

// ---------------------------------------------------------------------------
// Block per (b,n), 256 threads. s in LDS; o-phase coalesced rows + 1 butterfly
// per row (independent rows -> ILP); t-phase coalesced column walk.
//   mode 0: src=sp0 (uniform c=1/32) -> normalize -> t
//   mode 1: src=sp                    -> normalize -> t
//   mode 2: src=sp                    -> squash -> out
__global__ __launch_bounds__(256) void k_ot(const float* __restrict__ W,
                                            const float* __restrict__ src,
                                            float* __restrict__ tout,
                                            const int mode) {
    const int bn = blockIdx.x;
    const int b = bn >> 5, n = bn & 31;
    __shared__ float s_lds[ID];
    __shared__ float o_lds[DC];
    const int tid = threadIdx.x;
    const int wave = tid >> 6, lane = tid & 63;
    const float* Wn = W + (size_t)n * DC * ID;

    // s-reduce: thread k, coalesced
    float sv = 0.f;
    if (mode == 0) {
#pragma unroll
        for (int c = 0; c < CH; ++c) sv += src[(c * B + b) * ID + tid];
        sv *= (1.0f / NC);
    } else {
#pragma unroll
        for (int c = 0; c < CH; ++c)
            sv += src[((size_t)(c * B + b) * NC + n) * ID + tid];
    }
    s_lds[tid] = sv;
    __syncthreads();

    // o-phase: wave w owns rows w*16..w*16+15; lanes along k (float4).
    // s quad hoisted (1 LDS read); rows independent -> shuffle latency hidden.
    {
        const float4 s4 = *(const float4*)(s_lds + lane * 4);
#pragma unroll
        for (int rr = 0; rr < 16; ++rr) {
            const int d = wave * 16 + rr;
            const float4 w4 = *(const float4*)(Wn + (size_t)d * ID + lane * 4);
            float p = w4.x * s4.x + w4.y * s4.y + w4.z * s4.z + w4.w * s4.w;
#pragma unroll
            for (int off = 32; off > 0; off >>= 1) p += __shfl_xor(p, off);
            if (lane == 0) o_lds[d] = p;
        }
    }
    __syncthreads();

    // norm / squash factor on wave 0 (o_lds overwritten in place)
    if (wave == 0) {
        const float v = o_lds[lane];
        float sq = v * v;
#pragma unroll
        for (int off = 32; off > 0; off >>= 1) sq += __shfl_xor(sq, off);
        if (mode == 2) {
            const float s2 = sq + 1e-7f;
            o_lds[lane] = v * (sqrtf(s2) / (0.5f + s2));
        } else {
            o_lds[lane] = v / fmaxf(sqrtf(sq), 1e-12f);   // F.normalize
        }
    }
    __syncthreads();

    if (mode == 2) {
        if (tid < DC) tout[(size_t)(b * NC + n) * DC + tid] = o_lds[tid];
        return;
    }

    // t-phase: thread k, coalesced column walk; o broadcast from LDS
    float acc = 0.f;
    const float* wc = Wn + tid;
#pragma unroll
    for (int d = 0; d < DC; ++d) acc += wc[(size_t)d * ID] * o_lds[d];
    tout[((size_t)b * NC + n) * ID + tid] = acc;
}

// ---------------------------------------------------------------------------
// Fused logits (128i x 32n, K=256) -> softmax over n -> aggregate partials.
// Inner GEMM reads A (u) and B (t) straight from global; no staging barriers.
__global__ __launch_bounds__(256) void k_route(const float* __restrict__ u,
                                               const float* __restrict__ t,
                                               float* __restrict__ sp) {
    const int c = blockIdx.x, b = blockIdx.y;
    const int iBase = c * RIT;
    __shared__ float cl[RIT][36];
    const int tid = threadIdx.x;
    const int q = tid >> 3, r = tid & 7;   // 4 i x 4 n per thread
    const float4* u4 = (const float4*)(u + ((size_t)b * IN + iBase) * ID);
    const float4* t4 = (const float4*)(t + (size_t)b * NC * ID);

    float acc[4][4] = {{0.f}};
#pragma unroll 2
    for (int kq = 0; kq < ID / 4; ++kq) {
        const float4 A0 = u4[(size_t)(q * 4 + 0) * 64 + kq];
        const float4 A1 = u4[(size_t)(q * 4 + 1) * 64 + kq];
        const float4 A2 = u4[(size_t)(q * 4 + 2) * 64 + kq];
        const float4 A3 = u4[(size_t)(q * 4 + 3) * 64 + kq];
        const float4 B0 = t4[(size_t)(r * 4 + 0) * 64 + kq];
        const float4 B1 = t4[(size_t)(r * 4 + 1) * 64 + kq];
        const float4 B2 = t4[(size_t)(r * 4 + 2) * 64 + kq];
        const float4 B3 = t4[(size_t)(r * 4 + 3) * 64 + kq];
        const float4 Av[4] = {A0, A1, A2, A3};
        const float4 Bv[4] = {B0, B1, B2, B3};
#pragma unroll
        for (int ii = 0; ii < 4; ++ii)
#pragma unroll
            for (int jj = 0; jj < 4; ++jj)
                acc[ii][jj] += Av[ii].x * Bv[jj].x + Av[ii].y * Bv[jj].y
                             + Av[ii].z * Bv[jj].z + Av[ii].w * Bv[jj].w;
    }
#pragma unroll
    for (int ii = 0; ii < 4; ++ii)
#pragma unroll
        for (int jj = 0; jj < 4; ++jj)
            cl[q * 4 + ii][r * 4 + jj] = acc[ii][jj];
    __syncthreads();

    // softmax over 32 n per i (2 threads/i, 16 each)
    {
        const int i = tid >> 1, half = tid & 1;
        float v[16];
#pragma unroll
        for (int j = 0; j < 16; ++j) v[j] = cl[i][half * 16 + j];
        float mx = v[0];
#pragma unroll
        for (int j = 1; j < 16; ++j) mx = fmaxf(mx, v[j]);
        mx = fmaxf(mx, __shfl_xor(mx, 1));
        float sum = 0.f;
#pragma unroll
        for (int j = 0; j < 16; ++j) { v[j] = __expf(v[j] - mx); sum += v[j]; }
        sum += __shfl_xor(sum, 1);
        const float inv = 1.0f / sum;
#pragma unroll
        for (int j = 0; j < 16; ++j) cl[i][half * 16 + j] = v[j] * inv;
    }
    __syncthreads();

    // aggregate: thread owns 4 d (float4) x 8 n; u coalesced from L2/L3,
    // coefficients via wave-uniform LDS broadcast.
    const int d4 = tid & 63;
    const int ng = tid >> 6;
    float acc2[8][4] = {{0.f}};
    const float* up = u + ((size_t)b * IN + iBase) * ID + d4 * 4;
#pragma unroll 4
    for (int i = 0; i < RIT; ++i) {
        const float4 uv = *(const float4*)(up + (size_t)i * ID);
        const float4 c0 = *(const float4*)&cl[i][ng * 8];
        const float4 c1 = *(const float4*)&cl[i][ng * 8 + 4];
        const float cv[8] = {c0.x, c0.y, c0.z, c0.w, c1.x, c1.y, c1.z, c1.w};
        const float uvv[4] = {uv.x, uv.y, uv.z, uv.w};
#pragma unroll
        for (int j = 0; j < 8; ++j)
#pragma unroll
            for (int x = 0; x < 4; ++x) acc2[j][x] += cv[j] * uvv[x];
    }
    float* spb = sp + (size_t)(c * B + b) * NC * ID;
#pragma unroll
    for (int j = 0; j < 8; ++j)
        *(float4*)&spb[(size_t)(ng * 8 + j) * ID + d4 * 4] =
            make_float4(acc2[j][0], acc2[j][1], acc2[j][2], acc2[j][3]);
}

// ---------------------------------------------------------------------------
extern "C" void kernel_launch(void* const* d_in, const int* in_sizes, int n_in,
                              void* d_out, int out_size, void* d_ws, size_t ws_size,
                              hipStream_t stream) {
    const float* u = (const float*)d_in[0];   // [B][IN][ID]
    const float* W = (const float*)d_in[1];   // [NC*DC][ID]
    float* out = (float*)d_out;               // [B][NC][DC]

    float* ws  = (float*)d_ws;
    float* t   = ws;                                   // B*NC*ID    = 2 MB
    float* sp  = t  + (size_t)B * NC * ID;             // CH*B*NC*ID = 16 MB
    float* sp0 = sp + (size_t)CH * B * NC * ID;        // CH*B*ID    = 0.5 MB

    const dim3 blk(256);

    // iteration 0 (uniform c = 1/32)
    k_sumu <<<dim3(CH, B),   blk, 0, stream>>>(u, sp0);
    k_ot   <<<dim3(B * NC),  blk, 0, stream>>>(W, sp0, t, 0);
    // iteration 1
    k_route<<<dim3(CH, B),   blk, 0, stream>>>(u, t, sp);
    k_ot   <<<dim3(B * NC),  blk, 0, stream>>>(W, sp, t, 1);
    // iteration 2
    k_route<<<dim3(CH, B),   blk, 0, stream>>>(u, t, sp);
    k_ot   <<<dim3(B * NC),  blk, 0, stream>>>(W, sp, out, 2);
}